// Round 4
// baseline (1331.753 us; speedup 1.0000x reference)
//
#include <hip/hip_runtime.h>

#define N_NODES 100000
#define N_EDGES 1600000
#define NF 128
#define NC 16
#define NH 2
#define HC 32   // NH*NC
#define NL 2
#define NED 4
#define EPS 1e-5f
#define NEG 0.2f
#define SCAN_CH 512
#define NBLK ((N_NODES + SCAN_CH - 1) / SCAN_CH)   // 196

// ---- bf16 helpers (manual, RTN-even) -----------------------------------------
__device__ __forceinline__ unsigned short f2bf(float f) {
    unsigned int u = __float_as_uint(f);
    u += 0x7fffu + ((u >> 16) & 1u);
    return (unsigned short)(u >> 16);
}
__device__ __forceinline__ float bf2f(unsigned short u) {
    return __uint_as_float(((unsigned int)u) << 16);
}

// ---------------- embed: h = relu(node_LN(x @ W + b)) ; jk = h ----------------
__global__ __launch_bounds__(256) void k_embed(
    const float* __restrict__ x, const float* __restrict__ W,
    const float* __restrict__ b, const float* __restrict__ lnw,
    const float* __restrict__ lnb, float* __restrict__ h, float* __restrict__ jk)
{
    __shared__ float Ws[NF * NC];
    __shared__ float xs[16][NF + 4];
    const int t = threadIdx.x;
    for (int i = t; i < NF * NC; i += 256) Ws[i] = W[i];
    const int n0 = blockIdx.x * 16;
    for (int i = t; i < 16 * NF; i += 256) {
        int r = i >> 7, f = i & (NF - 1);
        int n = n0 + r;
        xs[r][f] = (n < N_NODES) ? x[(size_t)n * NF + f] : 0.f;
    }
    __syncthreads();
    const int r = t >> 4;
    const int c = t & 15;
    const int n = n0 + r;
    float acc = b[c];
#pragma unroll 16
    for (int f = 0; f < NF; ++f) acc += xs[r][f] * Ws[f * NC + c];
    float s = acc;
    for (int m = 8; m >= 1; m >>= 1) s += __shfl_xor(s, m, 16);
    float mu = s * (1.f / 16.f);
    float d = acc - mu;
    float v = d * d;
    for (int m = 8; m >= 1; m >>= 1) v += __shfl_xor(v, m, 16);
    float inv = rsqrtf(v * (1.f / 16.f) + EPS);
    float out = fmaxf(d * inv * lnw[c] + lnb[c], 0.f);
    if (n < N_NODES) {
        h[(size_t)n * NC + c]  = out;
        jk[(size_t)n * NC + c] = out;
    }
}

// ---------------- CSR build: histogram over dst -------------------------------
__global__ __launch_bounds__(256) void k_hist(
    const int* __restrict__ dst, int* __restrict__ counts)
{
    const int e = blockIdx.x * 256 + threadIdx.x;
    if (e < N_EDGES) atomicAdd(&counts[dst[e]], 1);
}

// ---- scan stage 1: per-512-chunk exclusive scan + chunk totals ---------------
__global__ __launch_bounds__(256) void k_scan1(
    const int* __restrict__ counts, int* __restrict__ scanned, int* __restrict__ bsums)
{
    __shared__ int tmp[256];
    const int b = blockIdx.x, t = threadIdx.x;
    const int i0 = b * SCAN_CH + 2 * t;
    int x0 = (i0 < N_NODES) ? counts[i0] : 0;
    int x1 = (i0 + 1 < N_NODES) ? counts[i0 + 1] : 0;
    int pair = x0 + x1;
    tmp[t] = pair;
    __syncthreads();
    for (int off = 1; off < 256; off <<= 1) {
        int v = (t >= off) ? tmp[t - off] : 0;
        __syncthreads();
        tmp[t] += v;
        __syncthreads();
    }
    int excl = tmp[t] - pair;
    if (i0 < N_NODES)     scanned[i0] = excl;
    if (i0 + 1 < N_NODES) scanned[i0 + 1] = excl + x0;
    if (t == 255) bsums[b] = tmp[t];
}

// ---- scan stage 2: exclusive scan of the NBLK chunk totals -------------------
__global__ __launch_bounds__(256) void k_scan2(
    const int* __restrict__ bsums, int* __restrict__ boffs)
{
    __shared__ int tmp[256];
    const int t = threadIdx.x;
    int v0 = (t < NBLK) ? bsums[t] : 0;
    tmp[t] = v0;
    __syncthreads();
    for (int off = 1; off < 256; off <<= 1) {
        int v = (t >= off) ? tmp[t - off] : 0;
        __syncthreads();
        tmp[t] += v;
        __syncthreads();
    }
    if (t < NBLK) boffs[t] = tmp[t] - v0;
}

// ---- scan stage 3: add chunk offsets; write offsets + cursors ----------------
__global__ __launch_bounds__(256) void k_scan3(
    const int* __restrict__ scanned, const int* __restrict__ boffs,
    int* __restrict__ offsets, int* __restrict__ cursors)
{
    const int i = blockIdx.x * 256 + threadIdx.x;
    if (i < N_NODES) {
        int v = scanned[i] + boffs[i / SCAN_CH];
        offsets[i] = v;
        cursors[i] = v;
    }
    if (i == 0) offsets[N_NODES] = N_EDGES;
}

// ---- scatter edges into CSR slots (src + reordered eattr) --------------------
__global__ __launch_bounds__(256) void k_scatter(
    const int* __restrict__ src, const int* __restrict__ dst,
    const float* __restrict__ eattr, int* __restrict__ cursors,
    int* __restrict__ csr_src, float4* __restrict__ csr_ea)
{
    const int e = blockIdx.x * 256 + threadIdx.x;
    if (e >= N_EDGES) return;
    const int d = dst[e];
    const int pos = atomicAdd(&cursors[d], 1);
    csr_src[pos] = src[e];
    csr_ea[pos] = *(const float4*)(eattr + (size_t)e * 4);
}

// ---- per-layer: xl/xr transforms (bf16 out) ----------------------------------
__global__ __launch_bounds__(256) void k_trans(
    const float* __restrict__ h, const float* __restrict__ Wl, const float* __restrict__ bl,
    const float* __restrict__ Wr, const float* __restrict__ br,
    unsigned short* __restrict__ xl, unsigned short* __restrict__ xr)
{
    __shared__ float Wls[NC * HC], Wrs[NC * HC];
    __shared__ float hs[8][NC + 1];
    const int t = threadIdx.x;
    for (int i = t; i < NC * HC; i += 256) { Wls[i] = Wl[i]; Wrs[i] = Wr[i]; }
    const int n0 = blockIdx.x * 8;
    for (int i = t; i < 8 * NC; i += 256) {
        int r = i >> 4, c = i & 15;
        int n = n0 + r;
        hs[r][c] = (n < N_NODES) ? h[(size_t)n * NC + c] : 0.f;
    }
    __syncthreads();
    const int r = t >> 5;
    const int j = t & 31;
    const int n = n0 + r;
    float al = bl[j], ar = br[j];
#pragma unroll
    for (int c = 0; c < NC; ++c) {
        float hv = hs[r][c];
        al += hv * Wls[c * HC + j];
        ar += hv * Wrs[c * HC + j];
    }
    if (n < N_NODES) {
        xl[(size_t)n * HC + j] = f2bf(al);
        xr[(size_t)n * HC + j] = f2bf(ar);
    }
}

// ---- atomic-free aggregation: 32 lanes per dst node; fused softmax+LN1 stats -
__global__ __launch_bounds__(256) void k_agg(
    const int* __restrict__ offsets, const int* __restrict__ csr_src,
    const float4* __restrict__ csr_ea,
    const float* __restrict__ We, const float* __restrict__ att,
    const float* __restrict__ gat_b,
    const unsigned short* __restrict__ xl, const unsigned short* __restrict__ xr,
    float* __restrict__ g, double* __restrict__ stats)
{
    __shared__ float Wes[NED * HC];
    __shared__ float atts[HC], gbs[HC];
    const int t = threadIdx.x;
    if (t < NED * HC) Wes[t] = We[t];
    if (t < HC) { atts[t] = att[t]; gbs[t] = gat_b[t]; }
    __syncthreads();
    const int grp = t >> 5;            // 0..7 local dst node
    const int j   = t & 31;            // channel (head*16+c)
    const int d = blockIdx.x * 8 + grp;
    float gv = 0.f;
    if (d < N_NODES) {
        const float aj = atts[j];
        const float xld = bf2f(xl[(size_t)d * HC + j]);
        const float xrd = bf2f(xr[(size_t)d * HC + j]);
        // self-loop (ew = 0)
        float m = xld + xrd;
        m = (m > 0.f) ? m : NEG * m;
        float p = m * aj;
        p += __shfl_xor(p, 1, 16); p += __shfl_xor(p, 2, 16);
        p += __shfl_xor(p, 4, 16); p += __shfl_xor(p, 8, 16);
        float eh = __expf(p);          // logits tiny: no segment-max needed
        float acc = eh * xld;
        float den = eh;
        const int base = offsets[d];
        const int end  = offsets[d + 1];
        for (int k = base; k < end; ++k) {
            const int s = csr_src[k];
            const float4 ea = csr_ea[k];
            const float xlv = bf2f(xl[(size_t)s * HC + j]);
            float mm = xlv + xrd
                     + ea.x * Wes[j] + ea.y * Wes[HC + j]
                     + ea.z * Wes[2 * HC + j] + ea.w * Wes[3 * HC + j];
            mm = (mm > 0.f) ? mm : NEG * mm;
            float pp = mm * aj;
            pp += __shfl_xor(pp, 1, 16); pp += __shfl_xor(pp, 2, 16);
            pp += __shfl_xor(pp, 4, 16); pp += __shfl_xor(pp, 8, 16);
            float ee = __expf(pp);
            acc += ee * xlv;
            den += ee;
        }
        gv = acc / den + gbs[j];
        g[(size_t)d * HC + j] = gv;
    }
    // fused graph-LN1 stats: block reduce + 2 double atomics
    float s = gv, ss = gv * gv;
    for (int m = 32; m >= 1; m >>= 1) { s += __shfl_xor(s, m); ss += __shfl_xor(ss, m); }
    __shared__ float sr[4], ssr[4];
    const int w = t >> 6;
    if ((t & 63) == 0) { sr[w] = s; ssr[w] = ss; }
    __syncthreads();
    if (t == 0) {
        atomicAdd(&stats[0], (double)(sr[0] + sr[1] + sr[2] + sr[3]));
        atomicAdd(&stats[1], (double)(ssr[0] + ssr[1] + ssr[2] + ssr[3]));
    }
}

// ---- apply LN1 + relu + linear(32->16) + stats for LN2 -----------------------
__global__ __launch_bounds__(256) void k_mid(
    const float* __restrict__ g,
    const float* __restrict__ n1w, const float* __restrict__ n1b,
    const float* __restrict__ linW, const float* __restrict__ linb,
    const double* __restrict__ stats1, float* __restrict__ g2,
    double* __restrict__ stats2)
{
    __shared__ float Ws[HC * NC];
    __shared__ float rs[16][HC + 1];
    const int t = threadIdx.x;
    for (int i = t; i < HC * NC; i += 256) Ws[i] = linW[i];
    const double cnt = (double)N_NODES * HC;
    const double mud = stats1[0] / cnt;
    const float mu  = (float)mud;
    const float var = (float)(stats1[1] / cnt - mud * mud);
    const float inv = rsqrtf(var + EPS);
    const int n0 = blockIdx.x * 16;
    for (int i = t; i < 16 * HC; i += 256) {
        int r = i >> 5, j = i & 31;
        int n = n0 + r;
        float v = (n < N_NODES) ? g[(size_t)n * HC + j] : mu;
        v = (v - mu) * inv * n1w[j] + n1b[j];
        rs[r][j] = fmaxf(v, 0.f);
    }
    __syncthreads();
    const int r = t >> 4, c = t & 15;
    const int n = n0 + r;
    float acc = linb[c];
#pragma unroll
    for (int j = 0; j < HC; ++j) acc += rs[r][j] * Ws[j * NC + c];
    float val = (n < N_NODES) ? acc : 0.f;
    if (n < N_NODES) g2[(size_t)n * NC + c] = acc;
    float s = val, ss = val * val;
    for (int m = 32; m >= 1; m >>= 1) { s += __shfl_xor(s, m); ss += __shfl_xor(ss, m); }
    __shared__ float sr[4], ssr[4];
    const int w = t >> 6;
    if ((t & 63) == 0) { sr[w] = s; ssr[w] = ss; }
    __syncthreads();
    if (t == 0) {
        atomicAdd(&stats2[0], (double)(sr[0] + sr[1] + sr[2] + sr[3]));
        atomicAdd(&stats2[1], (double)(ssr[0] + ssr[1] + ssr[2] + ssr[3]));
    }
}

// ---- apply LN2, residual + relu, update h and jk-max -------------------------
__global__ __launch_bounds__(256) void k_final(
    const float* __restrict__ g2, const float* __restrict__ n2w,
    const float* __restrict__ n2b, const double* __restrict__ stats2,
    float* __restrict__ h, float* __restrict__ jk)
{
    const int i = blockIdx.x * 256 + threadIdx.x;
    if (i >= N_NODES * NC) return;
    const double cnt = (double)N_NODES * NC;
    const double mud = stats2[0] / cnt;
    const float mu  = (float)mud;
    const float var = (float)(stats2[1] / cnt - mud * mud);
    const float inv = rsqrtf(var + EPS);
    const int c = i & (NC - 1);
    float v = (g2[i] - mu) * inv * n2w[c] + n2b[c];
    float hn = fmaxf(v + h[i], 0.f);
    h[i] = hn;
    jk[i] = fmaxf(jk[i], hn);
}

extern "C" void kernel_launch(void* const* d_in, const int* in_sizes, int n_in,
                              void* d_out, int out_size, void* d_ws, size_t ws_size,
                              hipStream_t stream)
{
    const float* x     = (const float*)d_in[0];
    const int*   eidx  = (const int*)d_in[1];
    const float* eattr = (const float*)d_in[2];
    const float* embW  = (const float*)d_in[3];
    const float* embB  = (const float*)d_in[4];
    const float* ln0w  = (const float*)d_in[5];
    const float* ln0b  = (const float*)d_in[6];
    const float* Wl    = (const float*)d_in[7];
    const float* bl    = (const float*)d_in[8];
    const float* Wr    = (const float*)d_in[9];
    const float* br    = (const float*)d_in[10];
    const float* We    = (const float*)d_in[11];
    const float* att   = (const float*)d_in[12];
    const float* gatb  = (const float*)d_in[13];
    const float* n1w   = (const float*)d_in[14];
    const float* n1b   = (const float*)d_in[15];
    const float* linW  = (const float*)d_in[16];
    const float* linb  = (const float*)d_in[17];
    const float* n2w   = (const float*)d_in[18];
    const float* n2b   = (const float*)d_in[19];
    float* out = (float*)d_out;

    // ---- workspace layout ----
    char* ws = (char*)d_ws;
    double* stats = (double*)ws;                       // 1 KB (zeroed per layer)
    char* p = ws + 1024;
    int* counts  = (int*)p;  p += (size_t)(N_NODES + 64) * 4;   // zeroed once
    int* scanned = (int*)p;  p += (size_t)(N_NODES + 64) * 4;
    int* bsums   = (int*)p;  p += 4096;
    int* boffs   = (int*)p;  p += 4096;
    int* offsets = (int*)p;  p += (size_t)(N_NODES + 64) * 4;
    int* cursors = (int*)p;  p += (size_t)(N_NODES + 64) * 4;
    int* csr_src = (int*)p;  p += (size_t)N_EDGES * 4;
    float4* csr_ea = (float4*)p; p += (size_t)N_EDGES * 16;
    float* h  = (float*)p;   p += (size_t)N_NODES * NC * 4;
    unsigned short* xl = (unsigned short*)p; p += (size_t)N_NODES * HC * 2;
    unsigned short* xr = (unsigned short*)p; p += (size_t)N_NODES * HC * 2;
    float* g   = (float*)p;  p += (size_t)N_NODES * HC * 4;
    float* g2  = (float*)p;  p += (size_t)N_NODES * NC * 4;

    const int* srcp = eidx;
    const int* dstp = eidx + N_EDGES;

    // CSR build (edge_index is layer-invariant: build once per call)
    hipMemsetAsync(counts, 0, (size_t)N_NODES * 4, stream);
    k_hist<<<(N_EDGES + 255) / 256, 256, 0, stream>>>(dstp, counts);
    k_scan1<<<NBLK, 256, 0, stream>>>(counts, scanned, bsums);
    k_scan2<<<1, 256, 0, stream>>>(bsums, boffs);
    k_scan3<<<(N_NODES + 255) / 256, 256, 0, stream>>>(scanned, boffs, offsets, cursors);
    k_scatter<<<(N_EDGES + 255) / 256, 256, 0, stream>>>(
        srcp, dstp, eattr, cursors, csr_src, csr_ea);

    k_embed<<<(N_NODES + 15) / 16, 256, 0, stream>>>(x, embW, embB, ln0w, ln0b, h, out);

    for (int l = 0; l < NL; ++l) {
        hipMemsetAsync(stats, 0, 1024, stream);
        k_trans<<<(N_NODES + 7) / 8, 256, 0, stream>>>(
            h, Wl + l * NC * HC, bl + l * HC, Wr + l * NC * HC, br + l * HC, xl, xr);
        k_agg<<<(N_NODES + 7) / 8, 256, 0, stream>>>(
            offsets, csr_src, csr_ea, We + l * NED * HC, att + l * HC,
            gatb + l * HC, xl, xr, g, stats);
        k_mid<<<(N_NODES + 15) / 16, 256, 0, stream>>>(
            g, n1w + l * HC, n1b + l * HC,
            linW + l * HC * NC, linb + l * NC, stats, g2, stats + 2);
        k_final<<<(N_NODES * NC + 255) / 256, 256, 0, stream>>>(
            g2, n2w + l * NC, n2b + l * NC, stats + 2, h, out);
    }
}

// Round 5
// 651.772 us; speedup vs baseline: 2.0433x; 2.0433x over previous
//
#include <hip/hip_runtime.h>

#define N_NODES 100000
#define N_EDGES 1600000
#define NF 128
#define NC 16
#define NH 2
#define HC 32   // NH*NC
#define NL 2
#define NED 4
#define EPS 1e-5f
#define NEG 0.2f
#define SCAN_CH 512
#define NBLK ((N_NODES + SCAN_CH - 1) / SCAN_CH)   // 196
#define AGG_BLKS ((N_NODES + 7) / 8)               // 12500
#define MID_BLKS ((N_NODES + 15) / 16)             // 6250

// ---- bf16 helpers (manual, RTN-even) -----------------------------------------
__device__ __forceinline__ unsigned short f2bf(float f) {
    unsigned int u = __float_as_uint(f);
    u += 0x7fffu + ((u >> 16) & 1u);
    return (unsigned short)(u >> 16);
}
__device__ __forceinline__ float bf2f(unsigned short u) {
    return __uint_as_float(((unsigned int)u) << 16);
}

// ---------------- embed: h = relu(node_LN(x @ W + b)) ; jk = h ----------------
__global__ __launch_bounds__(256) void k_embed(
    const float* __restrict__ x, const float* __restrict__ W,
    const float* __restrict__ b, const float* __restrict__ lnw,
    const float* __restrict__ lnb, float* __restrict__ h, float* __restrict__ jk)
{
    __shared__ float Ws[NF * NC];
    __shared__ float xs[16][NF + 4];
    const int t = threadIdx.x;
    for (int i = t; i < NF * NC; i += 256) Ws[i] = W[i];
    const int n0 = blockIdx.x * 16;
    for (int i = t; i < 16 * NF; i += 256) {
        int r = i >> 7, f = i & (NF - 1);
        int n = n0 + r;
        xs[r][f] = (n < N_NODES) ? x[(size_t)n * NF + f] : 0.f;
    }
    __syncthreads();
    const int r = t >> 4;
    const int c = t & 15;
    const int n = n0 + r;
    float acc = b[c];
#pragma unroll 16
    for (int f = 0; f < NF; ++f) acc += xs[r][f] * Ws[f * NC + c];
    float s = acc;
    for (int m = 8; m >= 1; m >>= 1) s += __shfl_xor(s, m, 16);
    float mu = s * (1.f / 16.f);
    float d = acc - mu;
    float v = d * d;
    for (int m = 8; m >= 1; m >>= 1) v += __shfl_xor(v, m, 16);
    float inv = rsqrtf(v * (1.f / 16.f) + EPS);
    float out = fmaxf(d * inv * lnw[c] + lnb[c], 0.f);
    if (n < N_NODES) {
        h[(size_t)n * NC + c]  = out;
        jk[(size_t)n * NC + c] = out;
    }
}

// ---------------- CSR build: histogram over dst -------------------------------
__global__ __launch_bounds__(256) void k_hist(
    const int* __restrict__ dst, int* __restrict__ counts)
{
    const int e = blockIdx.x * 256 + threadIdx.x;
    if (e < N_EDGES) atomicAdd(&counts[dst[e]], 1);
}

__global__ __launch_bounds__(256) void k_scan1(
    const int* __restrict__ counts, int* __restrict__ scanned, int* __restrict__ bsums)
{
    __shared__ int tmp[256];
    const int b = blockIdx.x, t = threadIdx.x;
    const int i0 = b * SCAN_CH + 2 * t;
    int x0 = (i0 < N_NODES) ? counts[i0] : 0;
    int x1 = (i0 + 1 < N_NODES) ? counts[i0 + 1] : 0;
    int pair = x0 + x1;
    tmp[t] = pair;
    __syncthreads();
    for (int off = 1; off < 256; off <<= 1) {
        int v = (t >= off) ? tmp[t - off] : 0;
        __syncthreads();
        tmp[t] += v;
        __syncthreads();
    }
    int excl = tmp[t] - pair;
    if (i0 < N_NODES)     scanned[i0] = excl;
    if (i0 + 1 < N_NODES) scanned[i0 + 1] = excl + x0;
    if (t == 255) bsums[b] = tmp[t];
}

__global__ __launch_bounds__(256) void k_scan2(
    const int* __restrict__ bsums, int* __restrict__ boffs)
{
    __shared__ int tmp[256];
    const int t = threadIdx.x;
    int v0 = (t < NBLK) ? bsums[t] : 0;
    tmp[t] = v0;
    __syncthreads();
    for (int off = 1; off < 256; off <<= 1) {
        int v = (t >= off) ? tmp[t - off] : 0;
        __syncthreads();
        tmp[t] += v;
        __syncthreads();
    }
    if (t < NBLK) boffs[t] = tmp[t] - v0;
}

__global__ __launch_bounds__(256) void k_scan3(
    const int* __restrict__ scanned, const int* __restrict__ boffs,
    int* __restrict__ offsets, int* __restrict__ cursors)
{
    const int i = blockIdx.x * 256 + threadIdx.x;
    if (i < N_NODES) {
        int v = scanned[i] + boffs[i / SCAN_CH];
        offsets[i] = v;
        cursors[i] = v;
    }
    if (i == 0) offsets[N_NODES] = N_EDGES;
}

// ---- scatter edges into CSR slots: int2{src, edge_id} (8 B) ------------------
__global__ __launch_bounds__(256) void k_scatter(
    const int* __restrict__ src, const int* __restrict__ dst,
    int* __restrict__ cursors, int2* __restrict__ csr_se)
{
    const int e = blockIdx.x * 256 + threadIdx.x;
    if (e >= N_EDGES) return;
    const int d = dst[e];
    const int pos = atomicAdd(&cursors[d], 1);
    csr_se[pos] = make_int2(src[e], e);
}

// ---- per-layer: xl/xr transforms (bf16 out) ----------------------------------
__global__ __launch_bounds__(256) void k_trans(
    const float* __restrict__ h, const float* __restrict__ Wl, const float* __restrict__ bl,
    const float* __restrict__ Wr, const float* __restrict__ br,
    unsigned short* __restrict__ xl, unsigned short* __restrict__ xr)
{
    __shared__ float Wls[NC * HC], Wrs[NC * HC];
    __shared__ float hs[8][NC + 1];
    const int t = threadIdx.x;
    for (int i = t; i < NC * HC; i += 256) { Wls[i] = Wl[i]; Wrs[i] = Wr[i]; }
    const int n0 = blockIdx.x * 8;
    for (int i = t; i < 8 * NC; i += 256) {
        int r = i >> 4, c = i & 15;
        int n = n0 + r;
        hs[r][c] = (n < N_NODES) ? h[(size_t)n * NC + c] : 0.f;
    }
    __syncthreads();
    const int r = t >> 5;
    const int j = t & 31;
    const int n = n0 + r;
    float al = bl[j], ar = br[j];
#pragma unroll
    for (int c = 0; c < NC; ++c) {
        float hv = hs[r][c];
        al += hv * Wls[c * HC + j];
        ar += hv * Wrs[c * HC + j];
    }
    if (n < N_NODES) {
        xl[(size_t)n * HC + j] = f2bf(al);
        xr[(size_t)n * HC + j] = f2bf(ar);
    }
}

// ---- head-logit reduce: sum over the 16 lanes of this head -------------------
__device__ __forceinline__ float head_sum(float p) {
    p += __shfl_xor(p, 1, 16);
    p += __shfl_xor(p, 2, 16);
    p += __shfl_xor(p, 4, 16);
    p += __shfl_xor(p, 8, 16);
    return p;
}

// ---- atomic-free aggregation, unroll-4 pipelined; partial LN1 stats ----------
__global__ __launch_bounds__(256) void k_agg(
    const int* __restrict__ offsets, const int2* __restrict__ csr_se,
    const float4* __restrict__ ea4,
    const float* __restrict__ We, const float* __restrict__ att,
    const float* __restrict__ gat_b,
    const unsigned short* __restrict__ xl, const unsigned short* __restrict__ xr,
    float* __restrict__ g, float2* __restrict__ part)
{
    __shared__ float Wes[NED * HC];
    __shared__ float atts[HC], gbs[HC];
    const int t = threadIdx.x;
    if (t < NED * HC) Wes[t] = We[t];
    if (t < HC) { atts[t] = att[t]; gbs[t] = gat_b[t]; }
    __syncthreads();
    const int grp = t >> 5;
    const int j   = t & 31;
    const int d = blockIdx.x * 8 + grp;
    float gv = 0.f;
    if (d < N_NODES) {
        const float aj = atts[j];
        const float w0 = Wes[j], w1 = Wes[HC + j], w2 = Wes[2 * HC + j], w3 = Wes[3 * HC + j];
        const float xld = bf2f(xl[(size_t)d * HC + j]);
        const float xrd = bf2f(xr[(size_t)d * HC + j]);
        // self-loop (ew = 0); logits tiny: exp without segment-max is exact enough
        float m = xld + xrd;
        m = (m > 0.f) ? m : NEG * m;
        float eh = __expf(head_sum(m * aj));
        float acc = eh * xld;
        float den = eh;
        const int base = offsets[d];
        const int deg  = offsets[d + 1] - base;
        int k = 0;
        for (; k + 4 <= deg; k += 4) {
            // issue all 12 loads up front: 4 independent gather chains
            const int2 s0 = csr_se[base + k];
            const int2 s1 = csr_se[base + k + 1];
            const int2 s2 = csr_se[base + k + 2];
            const int2 s3 = csr_se[base + k + 3];
            const float x0 = bf2f(xl[(size_t)s0.x * HC + j]);
            const float x1 = bf2f(xl[(size_t)s1.x * HC + j]);
            const float x2 = bf2f(xl[(size_t)s2.x * HC + j]);
            const float x3 = bf2f(xl[(size_t)s3.x * HC + j]);
            const float4 e0 = ea4[s0.y];
            const float4 e1 = ea4[s1.y];
            const float4 e2 = ea4[s2.y];
            const float4 e3 = ea4[s3.y];
            float m0 = x0 + xrd + e0.x * w0 + e0.y * w1 + e0.z * w2 + e0.w * w3;
            float m1 = x1 + xrd + e1.x * w0 + e1.y * w1 + e1.z * w2 + e1.w * w3;
            float m2 = x2 + xrd + e2.x * w0 + e2.y * w1 + e2.z * w2 + e2.w * w3;
            float m3 = x3 + xrd + e3.x * w0 + e3.y * w1 + e3.z * w2 + e3.w * w3;
            m0 = (m0 > 0.f) ? m0 : NEG * m0;
            m1 = (m1 > 0.f) ? m1 : NEG * m1;
            m2 = (m2 > 0.f) ? m2 : NEG * m2;
            m3 = (m3 > 0.f) ? m3 : NEG * m3;
            float p0 = m0 * aj, p1 = m1 * aj, p2 = m2 * aj, p3 = m3 * aj;
            // interleave the 4 shfl chains (independent DS ops pipeline)
            p0 += __shfl_xor(p0, 1, 16); p1 += __shfl_xor(p1, 1, 16);
            p2 += __shfl_xor(p2, 1, 16); p3 += __shfl_xor(p3, 1, 16);
            p0 += __shfl_xor(p0, 2, 16); p1 += __shfl_xor(p1, 2, 16);
            p2 += __shfl_xor(p2, 2, 16); p3 += __shfl_xor(p3, 2, 16);
            p0 += __shfl_xor(p0, 4, 16); p1 += __shfl_xor(p1, 4, 16);
            p2 += __shfl_xor(p2, 4, 16); p3 += __shfl_xor(p3, 4, 16);
            p0 += __shfl_xor(p0, 8, 16); p1 += __shfl_xor(p1, 8, 16);
            p2 += __shfl_xor(p2, 8, 16); p3 += __shfl_xor(p3, 8, 16);
            const float ee0 = __expf(p0), ee1 = __expf(p1);
            const float ee2 = __expf(p2), ee3 = __expf(p3);
            acc += ee0 * x0 + ee1 * x1 + ee2 * x2 + ee3 * x3;
            den += ee0 + ee1 + ee2 + ee3;
        }
        for (; k < deg; ++k) {
            const int2 se = csr_se[base + k];
            const float xv = bf2f(xl[(size_t)se.x * HC + j]);
            const float4 ea = ea4[se.y];
            float mm = xv + xrd + ea.x * w0 + ea.y * w1 + ea.z * w2 + ea.w * w3;
            mm = (mm > 0.f) ? mm : NEG * mm;
            const float ee = __expf(head_sum(mm * aj));
            acc += ee * xv;
            den += ee;
        }
        gv = acc / den + gbs[j];
        g[(size_t)d * HC + j] = gv;
    }
    // block-partial LN1 stats (plain store; no same-address atomics)
    float s = gv, ss = gv * gv;
    for (int m = 32; m >= 1; m >>= 1) { s += __shfl_xor(s, m); ss += __shfl_xor(ss, m); }
    __shared__ float sr[4], ssr[4];
    const int w = t >> 6;
    if ((t & 63) == 0) { sr[w] = s; ssr[w] = ss; }
    __syncthreads();
    if (t == 0) part[blockIdx.x] = make_float2(sr[0] + sr[1] + sr[2] + sr[3],
                                               ssr[0] + ssr[1] + ssr[2] + ssr[3]);
}

// ---- reduce block partials -> stats[0..1] ------------------------------------
__global__ __launch_bounds__(256) void k_red(
    const float2* __restrict__ part, int n, double* __restrict__ out)
{
    const int t = threadIdx.x;
    double s = 0.0, ss = 0.0;
    for (int i = t; i < n; i += 256) {
        float2 p = part[i];
        s += (double)p.x; ss += (double)p.y;
    }
    for (int m = 32; m >= 1; m >>= 1) { s += __shfl_xor(s, m); ss += __shfl_xor(ss, m); }
    __shared__ double sr[4], ssr[4];
    const int w = t >> 6;
    if ((t & 63) == 0) { sr[w] = s; ssr[w] = ss; }
    __syncthreads();
    if (t == 0) {
        out[0] = sr[0] + sr[1] + sr[2] + sr[3];
        out[1] = ssr[0] + ssr[1] + ssr[2] + ssr[3];
    }
}

// ---- apply LN1 + relu + linear(32->16) + partial stats for LN2 ---------------
__global__ __launch_bounds__(256) void k_mid(
    const float* __restrict__ g,
    const float* __restrict__ n1w, const float* __restrict__ n1b,
    const float* __restrict__ linW, const float* __restrict__ linb,
    const double* __restrict__ stats1, float* __restrict__ g2,
    float2* __restrict__ part)
{
    __shared__ float Ws[HC * NC];
    __shared__ float rs[16][HC + 1];
    const int t = threadIdx.x;
    for (int i = t; i < HC * NC; i += 256) Ws[i] = linW[i];
    const double cnt = (double)N_NODES * HC;
    const double mud = stats1[0] / cnt;
    const float mu  = (float)mud;
    const float var = (float)(stats1[1] / cnt - mud * mud);
    const float inv = rsqrtf(var + EPS);
    const int n0 = blockIdx.x * 16;
    for (int i = t; i < 16 * HC; i += 256) {
        int r = i >> 5, j = i & 31;
        int n = n0 + r;
        float v = (n < N_NODES) ? g[(size_t)n * HC + j] : mu;
        v = (v - mu) * inv * n1w[j] + n1b[j];
        rs[r][j] = fmaxf(v, 0.f);
    }
    __syncthreads();
    const int r = t >> 4, c = t & 15;
    const int n = n0 + r;
    float acc = linb[c];
#pragma unroll
    for (int j = 0; j < HC; ++j) acc += rs[r][j] * Ws[j * NC + c];
    float val = (n < N_NODES) ? acc : 0.f;
    if (n < N_NODES) g2[(size_t)n * NC + c] = acc;
    float s = val, ss = val * val;
    for (int m = 32; m >= 1; m >>= 1) { s += __shfl_xor(s, m); ss += __shfl_xor(ss, m); }
    __shared__ float sr[4], ssr[4];
    const int w = t >> 6;
    if ((t & 63) == 0) { sr[w] = s; ssr[w] = ss; }
    __syncthreads();
    if (t == 0) part[blockIdx.x] = make_float2(sr[0] + sr[1] + sr[2] + sr[3],
                                               ssr[0] + ssr[1] + ssr[2] + ssr[3]);
}

// ---- apply LN2, residual + relu, update h and jk-max -------------------------
__global__ __launch_bounds__(256) void k_final(
    const float* __restrict__ g2, const float* __restrict__ n2w,
    const float* __restrict__ n2b, const double* __restrict__ stats2,
    float* __restrict__ h, float* __restrict__ jk)
{
    const int i = blockIdx.x * 256 + threadIdx.x;
    if (i >= N_NODES * NC) return;
    const double cnt = (double)N_NODES * NC;
    const double mud = stats2[0] / cnt;
    const float mu  = (float)mud;
    const float var = (float)(stats2[1] / cnt - mud * mud);
    const float inv = rsqrtf(var + EPS);
    const int c = i & (NC - 1);
    float v = (g2[i] - mu) * inv * n2w[c] + n2b[c];
    float hn = fmaxf(v + h[i], 0.f);
    h[i] = hn;
    jk[i] = fmaxf(jk[i], hn);
}

extern "C" void kernel_launch(void* const* d_in, const int* in_sizes, int n_in,
                              void* d_out, int out_size, void* d_ws, size_t ws_size,
                              hipStream_t stream)
{
    const float* x     = (const float*)d_in[0];
    const int*   eidx  = (const int*)d_in[1];
    const float* eattr = (const float*)d_in[2];
    const float* embW  = (const float*)d_in[3];
    const float* embB  = (const float*)d_in[4];
    const float* ln0w  = (const float*)d_in[5];
    const float* ln0b  = (const float*)d_in[6];
    const float* Wl    = (const float*)d_in[7];
    const float* bl    = (const float*)d_in[8];
    const float* Wr    = (const float*)d_in[9];
    const float* br    = (const float*)d_in[10];
    const float* We    = (const float*)d_in[11];
    const float* att   = (const float*)d_in[12];
    const float* gatb  = (const float*)d_in[13];
    const float* n1w   = (const float*)d_in[14];
    const float* n1b   = (const float*)d_in[15];
    const float* linW  = (const float*)d_in[16];
    const float* linb  = (const float*)d_in[17];
    const float* n2w   = (const float*)d_in[18];
    const float* n2b   = (const float*)d_in[19];
    float* out = (float*)d_out;

    // ---- workspace layout ----
    char* ws = (char*)d_ws;
    double* stats = (double*)ws;                       // 1 KB (written by k_red)
    char* p = ws + 1024;
    int* counts  = (int*)p;  p += (size_t)(N_NODES + 64) * 4;   // zeroed once
    int* scanned = (int*)p;  p += (size_t)(N_NODES + 64) * 4;
    int* bsums   = (int*)p;  p += 4096;
    int* boffs   = (int*)p;  p += 4096;
    int* offsets = (int*)p;  p += (size_t)(N_NODES + 64) * 4;
    int* cursors = (int*)p;  p += (size_t)(N_NODES + 64) * 4;
    int2* csr_se = (int2*)p; p += (size_t)N_EDGES * 8;
    float* h  = (float*)p;   p += (size_t)N_NODES * NC * 4;
    unsigned short* xl = (unsigned short*)p; p += (size_t)N_NODES * HC * 2;
    unsigned short* xr = (unsigned short*)p; p += (size_t)N_NODES * HC * 2;
    float* g   = (float*)p;  p += (size_t)N_NODES * HC * 4;
    float* g2  = (float*)p;  p += (size_t)N_NODES * NC * 4;
    float2* part1 = (float2*)p; p += (size_t)AGG_BLKS * 8;
    float2* part2 = (float2*)p; p += (size_t)MID_BLKS * 8;

    const int* srcp = eidx;
    const int* dstp = eidx + N_EDGES;

    // CSR build (edge_index is layer-invariant: build once per call)
    hipMemsetAsync(counts, 0, (size_t)N_NODES * 4, stream);
    k_hist<<<(N_EDGES + 255) / 256, 256, 0, stream>>>(dstp, counts);
    k_scan1<<<NBLK, 256, 0, stream>>>(counts, scanned, bsums);
    k_scan2<<<1, 256, 0, stream>>>(bsums, boffs);
    k_scan3<<<(N_NODES + 255) / 256, 256, 0, stream>>>(scanned, boffs, offsets, cursors);
    k_scatter<<<(N_EDGES + 255) / 256, 256, 0, stream>>>(srcp, dstp, cursors, csr_se);

    k_embed<<<(N_NODES + 15) / 16, 256, 0, stream>>>(x, embW, embB, ln0w, ln0b, h, out);

    for (int l = 0; l < NL; ++l) {
        k_trans<<<(N_NODES + 7) / 8, 256, 0, stream>>>(
            h, Wl + l * NC * HC, bl + l * HC, Wr + l * NC * HC, br + l * HC, xl, xr);
        k_agg<<<AGG_BLKS, 256, 0, stream>>>(
            offsets, csr_se, (const float4*)eattr, We + l * NED * HC, att + l * HC,
            gatb + l * HC, xl, xr, g, part1);
        k_red<<<1, 256, 0, stream>>>(part1, AGG_BLKS, stats);
        k_mid<<<MID_BLKS, 256, 0, stream>>>(
            g, n1w + l * HC, n1b + l * HC,
            linW + l * HC * NC, linb + l * NC, stats, g2, part2);
        k_red<<<1, 256, 0, stream>>>(part2, MID_BLKS, stats + 2);
        k_final<<<(N_NODES * NC + 255) / 256, 256, 0, stream>>>(
            g2, n2w + l * NC, n2b + l * NC, stats + 2, h, out);
    }
}

// Round 6
// 516.263 us; speedup vs baseline: 2.5796x; 1.2625x over previous
//
#include <hip/hip_runtime.h>

#define N_NODES 100000
#define N_EDGES 1600000
#define NF 128
#define NC 16
#define NH 2
#define HC 32   // NH*NC
#define NL 2
#define NED 4
#define EPS 1e-5f
#define NEG 0.2f
#define NBUCK 196                    // ceil(N_NODES / 512)
#define P1_CHUNK 4096
#define P1_BLKS ((N_EDGES + P1_CHUNK - 1) / P1_CHUNK)   // 391
#define AGG_BLKS ((N_NODES + 7) / 8)               // 12500
#define MID_BLKS ((N_NODES + 15) / 16)             // 6250

// ---- bf16 helpers (manual, RTN-even) -----------------------------------------
__device__ __forceinline__ unsigned short f2bf(float f) {
    unsigned int u = __float_as_uint(f);
    u += 0x7fffu + ((u >> 16) & 1u);
    return (unsigned short)(u >> 16);
}
__device__ __forceinline__ float bf2f(unsigned short u) {
    return __uint_as_float(((unsigned int)u) << 16);
}

// ---------------- embed: h = relu(node_LN(x @ W + b)) ; jk = h ----------------
__global__ __launch_bounds__(256) void k_embed(
    const float* __restrict__ x, const float* __restrict__ W,
    const float* __restrict__ b, const float* __restrict__ lnw,
    const float* __restrict__ lnb, float* __restrict__ h, float* __restrict__ jk)
{
    __shared__ float Ws[NF * NC];
    __shared__ float xs[16][NF + 4];
    const int t = threadIdx.x;
    for (int i = t; i < NF * NC; i += 256) Ws[i] = W[i];
    const int n0 = blockIdx.x * 16;
    for (int i = t; i < 16 * NF; i += 256) {
        int r = i >> 7, f = i & (NF - 1);
        int n = n0 + r;
        xs[r][f] = (n < N_NODES) ? x[(size_t)n * NF + f] : 0.f;
    }
    __syncthreads();
    const int r = t >> 4;
    const int c = t & 15;
    const int n = n0 + r;
    float acc = b[c];
#pragma unroll 16
    for (int f = 0; f < NF; ++f) acc += xs[r][f] * Ws[f * NC + c];
    float s = acc;
    for (int m = 8; m >= 1; m >>= 1) s += __shfl_xor(s, m, 16);
    float mu = s * (1.f / 16.f);
    float d = acc - mu;
    float v = d * d;
    for (int m = 8; m >= 1; m >>= 1) v += __shfl_xor(v, m, 16);
    float inv = rsqrtf(v * (1.f / 16.f) + EPS);
    float out = fmaxf(d * inv * lnw[c] + lnb[c], 0.f);
    if (n < N_NODES) {
        h[(size_t)n * NC + c]  = out;
        jk[(size_t)n * NC + c] = out;
    }
}

// ---- bucket histogram (bucket = dst >> 9), LDS-staged ------------------------
__global__ __launch_bounds__(256) void k_bhist(
    const int* __restrict__ dst, int* __restrict__ bcnt)
{
    __shared__ int hist[256];
    const int t = threadIdx.x;
    hist[t] = 0;
    __syncthreads();
    const int e0 = blockIdx.x * P1_CHUNK;
    const int cnt = min(P1_CHUNK, N_EDGES - e0);
    for (int i = t; i < cnt; i += 256)
        atomicAdd(&hist[dst[e0 + i] >> 9], 1);
    __syncthreads();
    if (hist[t] > 0) atomicAdd(&bcnt[t], hist[t]);
}

// ---- scan 196 bucket counts -> bases + working cursors -----------------------
__global__ __launch_bounds__(256) void k_bscan(
    const int* __restrict__ bcnt, int* __restrict__ bbase, int* __restrict__ bcur)
{
    __shared__ int tmp[256];
    const int t = threadIdx.x;
    int v0 = bcnt[t];
    tmp[t] = v0;
    __syncthreads();
    for (int off = 1; off < 256; off <<= 1) {
        int v = (t >= off) ? tmp[t - off] : 0;
        __syncthreads();
        tmp[t] += v;
        __syncthreads();
    }
    int excl = tmp[t] - v0;
    bbase[t] = excl;
    bcur[t]  = excl;
    if (t == 255) bbase[256] = tmp[t];   // == N_EDGES
}

// ---- pass1: LDS-staged bucket scatter (coalesced bucket-run flushes) ---------
// staged payload: {src, (e<<9)|dst_local}; e < 2^21, dst_local < 512
__global__ __launch_bounds__(256) void k_pass1(
    const int* __restrict__ src, const int* __restrict__ dst,
    int* __restrict__ bcur, int2* __restrict__ csr_tmp)
{
    __shared__ int2 stage[P1_CHUNK];                 // 32 KB
    __shared__ unsigned char bstage[P1_CHUNK];       // 4 KB
    __shared__ int hist[256];                        // counts -> cursors
    __shared__ int exc[256];
    __shared__ int gbase[256];
    __shared__ int scanbuf[256];
    const int t = threadIdx.x;
    const int e0 = blockIdx.x * P1_CHUNK;
    const int cnt = min(P1_CHUNK, N_EDGES - e0);
    hist[t] = 0;
    __syncthreads();
    int mys[16], myb[16], myp[16];
    int nv = 0;
#pragma unroll
    for (int k = 0; k < 16; ++k) {
        int i = k * 256 + t;
        if (i < cnt) {
            int e = e0 + i;
            int d = dst[e];
            mys[nv] = src[e];
            myb[nv] = d >> 9;
            myp[nv] = (e << 9) | (d & 511);
            atomicAdd(&hist[d >> 9], 1);
            ++nv;
        }
    }
    __syncthreads();
    // exclusive scan of hist
    int hv = hist[t];
    scanbuf[t] = hv;
    __syncthreads();
    for (int off = 1; off < 256; off <<= 1) {
        int v = (t >= off) ? scanbuf[t - off] : 0;
        __syncthreads();
        scanbuf[t] += v;
        __syncthreads();
    }
    int ex = scanbuf[t] - hv;
    hist[t] = ex;            // becomes local cursor
    exc[t]  = ex;
    __syncthreads();
    // place into stage in bucket-sorted order
    for (int k = 0; k < nv; ++k) {
        int pos = atomicAdd(&hist[myb[k]], 1);
        stage[pos]  = make_int2(mys[k], myp[k]);
        bstage[pos] = (unsigned char)myb[k];
    }
    __syncthreads();
    // reserve global space: one atomic per touched bucket
    {
        int c = hist[t] - exc[t];
        gbase[t] = (c > 0) ? atomicAdd(&bcur[t], c) : 0;
    }
    __syncthreads();
    // flush: consecutive i within a bucket run -> consecutive global slots
    for (int i = t; i < cnt; i += 256) {
        int b = bstage[i];
        csr_tmp[gbase[b] + (i - exc[b])] = stage[i];
    }
}

// ---- pass2: one block per bucket; per-dst LDS hist+scan -> offsets + CSR -----
__global__ __launch_bounds__(256) void k_pass2(
    const int* __restrict__ bbase, const int2* __restrict__ csr_tmp,
    int* __restrict__ offsets, int2* __restrict__ csr_se)
{
    __shared__ int hist[512];
    __shared__ int cur[512];
    __shared__ int scanbuf[256];
    const int b = blockIdx.x, t = threadIdx.x;
    const int ebeg = bbase[b], eend = bbase[b + 1];
    hist[t] = 0; hist[t + 256] = 0;
    __syncthreads();
    for (int i = ebeg + t; i < eend; i += 256)
        atomicAdd(&hist[csr_tmp[i].y & 511], 1);
    __syncthreads();
    // exclusive scan over 512 (2 per thread)
    int a0 = hist[2 * t], a1 = hist[2 * t + 1];
    int pair = a0 + a1;
    scanbuf[t] = pair;
    __syncthreads();
    for (int off = 1; off < 256; off <<= 1) {
        int v = (t >= off) ? scanbuf[t - off] : 0;
        __syncthreads();
        scanbuf[t] += v;
        __syncthreads();
    }
    int e2 = scanbuf[t] - pair;
    cur[2 * t]     = e2;
    cur[2 * t + 1] = e2 + a0;
    __syncthreads();
    // write offsets for this bucket's nodes
    const int n0 = b * 512;
#pragma unroll
    for (int k = 0; k < 2; ++k) {
        int i = t + k * 256;
        int n = n0 + i;
        if (n < N_NODES) offsets[n] = ebeg + cur[i];
    }
    if (b == NBUCK - 1 && t == 0) offsets[N_NODES] = N_EDGES;
    __syncthreads();
    // permute into final CSR order (writes stay in this bucket's ~65KB window)
    for (int i = ebeg + t; i < eend; i += 256) {
        int2 se = csr_tmp[i];
        int dl = se.y & 511;
        int e  = (int)(((unsigned int)se.y) >> 9);
        int pos = ebeg + atomicAdd(&cur[dl], 1);
        csr_se[pos] = make_int2(se.x, e);
    }
}

// ---- per-layer: xl/xr transforms (bf16 out) ----------------------------------
__global__ __launch_bounds__(256) void k_trans(
    const float* __restrict__ h, const float* __restrict__ Wl, const float* __restrict__ bl,
    const float* __restrict__ Wr, const float* __restrict__ br,
    unsigned short* __restrict__ xl, unsigned short* __restrict__ xr)
{
    __shared__ float Wls[NC * HC], Wrs[NC * HC];
    __shared__ float hs[8][NC + 1];
    const int t = threadIdx.x;
    for (int i = t; i < NC * HC; i += 256) { Wls[i] = Wl[i]; Wrs[i] = Wr[i]; }
    const int n0 = blockIdx.x * 8;
    for (int i = t; i < 8 * NC; i += 256) {
        int r = i >> 4, c = i & 15;
        int n = n0 + r;
        hs[r][c] = (n < N_NODES) ? h[(size_t)n * NC + c] : 0.f;
    }
    __syncthreads();
    const int r = t >> 5;
    const int j = t & 31;
    const int n = n0 + r;
    float al = bl[j], ar = br[j];
#pragma unroll
    for (int c = 0; c < NC; ++c) {
        float hv = hs[r][c];
        al += hv * Wls[c * HC + j];
        ar += hv * Wrs[c * HC + j];
    }
    if (n < N_NODES) {
        xl[(size_t)n * HC + j] = f2bf(al);
        xr[(size_t)n * HC + j] = f2bf(ar);
    }
}

// ---- head-logit reduce: sum over the 16 lanes of this head -------------------
__device__ __forceinline__ float head_sum(float p) {
    p += __shfl_xor(p, 1, 16);
    p += __shfl_xor(p, 2, 16);
    p += __shfl_xor(p, 4, 16);
    p += __shfl_xor(p, 8, 16);
    return p;
}

// ---- atomic-free aggregation, unroll-4 pipelined; partial LN1 stats ----------
__global__ __launch_bounds__(256) void k_agg(
    const int* __restrict__ offsets, const int2* __restrict__ csr_se,
    const float4* __restrict__ ea4,
    const float* __restrict__ We, const float* __restrict__ att,
    const float* __restrict__ gat_b,
    const unsigned short* __restrict__ xl, const unsigned short* __restrict__ xr,
    float* __restrict__ g, float2* __restrict__ part)
{
    __shared__ float Wes[NED * HC];
    __shared__ float atts[HC], gbs[HC];
    const int t = threadIdx.x;
    if (t < NED * HC) Wes[t] = We[t];
    if (t < HC) { atts[t] = att[t]; gbs[t] = gat_b[t]; }
    __syncthreads();
    const int grp = t >> 5;
    const int j   = t & 31;
    const int d = blockIdx.x * 8 + grp;
    float gv = 0.f;
    if (d < N_NODES) {
        const float aj = atts[j];
        const float w0 = Wes[j], w1 = Wes[HC + j], w2 = Wes[2 * HC + j], w3 = Wes[3 * HC + j];
        const float xld = bf2f(xl[(size_t)d * HC + j]);
        const float xrd = bf2f(xr[(size_t)d * HC + j]);
        // self-loop (ew = 0); logits tiny: exp without segment-max is exact enough
        float m = xld + xrd;
        m = (m > 0.f) ? m : NEG * m;
        float eh = __expf(head_sum(m * aj));
        float acc = eh * xld;
        float den = eh;
        const int base = offsets[d];
        const int deg  = offsets[d + 1] - base;
        int k = 0;
        for (; k + 4 <= deg; k += 4) {
            const int2 s0 = csr_se[base + k];
            const int2 s1 = csr_se[base + k + 1];
            const int2 s2 = csr_se[base + k + 2];
            const int2 s3 = csr_se[base + k + 3];
            const float x0 = bf2f(xl[(size_t)s0.x * HC + j]);
            const float x1 = bf2f(xl[(size_t)s1.x * HC + j]);
            const float x2 = bf2f(xl[(size_t)s2.x * HC + j]);
            const float x3 = bf2f(xl[(size_t)s3.x * HC + j]);
            const float4 e0 = ea4[s0.y];
            const float4 e1 = ea4[s1.y];
            const float4 e2 = ea4[s2.y];
            const float4 e3 = ea4[s3.y];
            float m0 = x0 + xrd + e0.x * w0 + e0.y * w1 + e0.z * w2 + e0.w * w3;
            float m1 = x1 + xrd + e1.x * w0 + e1.y * w1 + e1.z * w2 + e1.w * w3;
            float m2 = x2 + xrd + e2.x * w0 + e2.y * w1 + e2.z * w2 + e2.w * w3;
            float m3 = x3 + xrd + e3.x * w0 + e3.y * w1 + e3.z * w2 + e3.w * w3;
            m0 = (m0 > 0.f) ? m0 : NEG * m0;
            m1 = (m1 > 0.f) ? m1 : NEG * m1;
            m2 = (m2 > 0.f) ? m2 : NEG * m2;
            m3 = (m3 > 0.f) ? m3 : NEG * m3;
            float p0 = m0 * aj, p1 = m1 * aj, p2 = m2 * aj, p3 = m3 * aj;
            p0 += __shfl_xor(p0, 1, 16); p1 += __shfl_xor(p1, 1, 16);
            p2 += __shfl_xor(p2, 1, 16); p3 += __shfl_xor(p3, 1, 16);
            p0 += __shfl_xor(p0, 2, 16); p1 += __shfl_xor(p1, 2, 16);
            p2 += __shfl_xor(p2, 2, 16); p3 += __shfl_xor(p3, 2, 16);
            p0 += __shfl_xor(p0, 4, 16); p1 += __shfl_xor(p1, 4, 16);
            p2 += __shfl_xor(p2, 4, 16); p3 += __shfl_xor(p3, 4, 16);
            p0 += __shfl_xor(p0, 8, 16); p1 += __shfl_xor(p1, 8, 16);
            p2 += __shfl_xor(p2, 8, 16); p3 += __shfl_xor(p3, 8, 16);
            const float ee0 = __expf(p0), ee1 = __expf(p1);
            const float ee2 = __expf(p2), ee3 = __expf(p3);
            acc += ee0 * x0 + ee1 * x1 + ee2 * x2 + ee3 * x3;
            den += ee0 + ee1 + ee2 + ee3;
        }
        for (; k < deg; ++k) {
            const int2 se = csr_se[base + k];
            const float xv = bf2f(xl[(size_t)se.x * HC + j]);
            const float4 ea = ea4[se.y];
            float mm = xv + xrd + ea.x * w0 + ea.y * w1 + ea.z * w2 + ea.w * w3;
            mm = (mm > 0.f) ? mm : NEG * mm;
            const float ee = __expf(head_sum(mm * aj));
            acc += ee * xv;
            den += ee;
        }
        gv = acc / den + gbs[j];
        g[(size_t)d * HC + j] = gv;
    }
    float s = gv, ss = gv * gv;
    for (int m = 32; m >= 1; m >>= 1) { s += __shfl_xor(s, m); ss += __shfl_xor(ss, m); }
    __shared__ float sr[4], ssr[4];
    const int w = t >> 6;
    if ((t & 63) == 0) { sr[w] = s; ssr[w] = ss; }
    __syncthreads();
    if (t == 0) part[blockIdx.x] = make_float2(sr[0] + sr[1] + sr[2] + sr[3],
                                               ssr[0] + ssr[1] + ssr[2] + ssr[3]);
}

// ---- reduce block partials -> stats[0..1] ------------------------------------
__global__ __launch_bounds__(256) void k_red(
    const float2* __restrict__ part, int n, double* __restrict__ out)
{
    const int t = threadIdx.x;
    double s = 0.0, ss = 0.0;
    for (int i = t; i < n; i += 256) {
        float2 p = part[i];
        s += (double)p.x; ss += (double)p.y;
    }
    for (int m = 32; m >= 1; m >>= 1) { s += __shfl_xor(s, m); ss += __shfl_xor(ss, m); }
    __shared__ double sr[4], ssr[4];
    const int w = t >> 6;
    if ((t & 63) == 0) { sr[w] = s; ssr[w] = ss; }
    __syncthreads();
    if (t == 0) {
        out[0] = sr[0] + sr[1] + sr[2] + sr[3];
        out[1] = ssr[0] + ssr[1] + ssr[2] + ssr[3];
    }
}

// ---- apply LN1 + relu + linear(32->16) + partial stats for LN2 ---------------
__global__ __launch_bounds__(256) void k_mid(
    const float* __restrict__ g,
    const float* __restrict__ n1w, const float* __restrict__ n1b,
    const float* __restrict__ linW, const float* __restrict__ linb,
    const double* __restrict__ stats1, float* __restrict__ g2,
    float2* __restrict__ part)
{
    __shared__ float Ws[HC * NC];
    __shared__ float rs[16][HC + 1];
    const int t = threadIdx.x;
    for (int i = t; i < HC * NC; i += 256) Ws[i] = linW[i];
    const double cnt = (double)N_NODES * HC;
    const double mud = stats1[0] / cnt;
    const float mu  = (float)mud;
    const float var = (float)(stats1[1] / cnt - mud * mud);
    const float inv = rsqrtf(var + EPS);
    const int n0 = blockIdx.x * 16;
    for (int i = t; i < 16 * HC; i += 256) {
        int r = i >> 5, j = i & 31;
        int n = n0 + r;
        float v = (n < N_NODES) ? g[(size_t)n * HC + j] : mu;
        v = (v - mu) * inv * n1w[j] + n1b[j];
        rs[r][j] = fmaxf(v, 0.f);
    }
    __syncthreads();
    const int r = t >> 4, c = t & 15;
    const int n = n0 + r;
    float acc = linb[c];
#pragma unroll
    for (int j = 0; j < HC; ++j) acc += rs[r][j] * Ws[j * NC + c];
    float val = (n < N_NODES) ? acc : 0.f;
    if (n < N_NODES) g2[(size_t)n * NC + c] = acc;
    float s = val, ss = val * val;
    for (int m = 32; m >= 1; m >>= 1) { s += __shfl_xor(s, m); ss += __shfl_xor(ss, m); }
    __shared__ float sr[4], ssr[4];
    const int w = t >> 6;
    if ((t & 63) == 0) { sr[w] = s; ssr[w] = ss; }
    __syncthreads();
    if (t == 0) part[blockIdx.x] = make_float2(sr[0] + sr[1] + sr[2] + sr[3],
                                               ssr[0] + ssr[1] + ssr[2] + ssr[3]);
}

// ---- apply LN2, residual + relu, update h and jk-max -------------------------
__global__ __launch_bounds__(256) void k_final(
    const float* __restrict__ g2, const float* __restrict__ n2w,
    const float* __restrict__ n2b, const double* __restrict__ stats2,
    float* __restrict__ h, float* __restrict__ jk)
{
    const int i = blockIdx.x * 256 + threadIdx.x;
    if (i >= N_NODES * NC) return;
    const double cnt = (double)N_NODES * NC;
    const double mud = stats2[0] / cnt;
    const float mu  = (float)mud;
    const float var = (float)(stats2[1] / cnt - mud * mud);
    const float inv = rsqrtf(var + EPS);
    const int c = i & (NC - 1);
    float v = (g2[i] - mu) * inv * n2w[c] + n2b[c];
    float hn = fmaxf(v + h[i], 0.f);
    h[i] = hn;
    jk[i] = fmaxf(jk[i], hn);
}

extern "C" void kernel_launch(void* const* d_in, const int* in_sizes, int n_in,
                              void* d_out, int out_size, void* d_ws, size_t ws_size,
                              hipStream_t stream)
{
    const float* x     = (const float*)d_in[0];
    const int*   eidx  = (const int*)d_in[1];
    const float* eattr = (const float*)d_in[2];
    const float* embW  = (const float*)d_in[3];
    const float* embB  = (const float*)d_in[4];
    const float* ln0w  = (const float*)d_in[5];
    const float* ln0b  = (const float*)d_in[6];
    const float* Wl    = (const float*)d_in[7];
    const float* bl    = (const float*)d_in[8];
    const float* Wr    = (const float*)d_in[9];
    const float* br    = (const float*)d_in[10];
    const float* We    = (const float*)d_in[11];
    const float* att   = (const float*)d_in[12];
    const float* gatb  = (const float*)d_in[13];
    const float* n1w   = (const float*)d_in[14];
    const float* n1b   = (const float*)d_in[15];
    const float* linW  = (const float*)d_in[16];
    const float* linb  = (const float*)d_in[17];
    const float* n2w   = (const float*)d_in[18];
    const float* n2b   = (const float*)d_in[19];
    float* out = (float*)d_out;

    // ---- workspace layout ----
    char* ws = (char*)d_ws;
    double* stats = (double*)ws;                       // written by k_red
    char* p = ws + 1024;
    int* bcnt  = (int*)p;  p += 1024;                  // 256 ints, zeroed
    int* bbase = (int*)p;  p += 2048;                  // 257 ints
    int* bcur  = (int*)p;  p += 1024;                  // 256 ints
    int* offsets = (int*)p; p += (size_t)(N_NODES + 64) * 4;
    int2* csr_tmp = (int2*)p; p += (size_t)N_EDGES * 8;
    int2* csr_se  = (int2*)p; p += (size_t)N_EDGES * 8;
    float* h  = (float*)p;   p += (size_t)N_NODES * NC * 4;
    unsigned short* xl = (unsigned short*)p; p += (size_t)N_NODES * HC * 2;
    unsigned short* xr = (unsigned short*)p; p += (size_t)N_NODES * HC * 2;
    float* g   = (float*)p;  p += (size_t)N_NODES * HC * 4;
    float* g2  = (float*)p;  p += (size_t)N_NODES * NC * 4;
    float2* part1 = (float2*)p; p += (size_t)AGG_BLKS * 8;
    float2* part2 = (float2*)p; p += (size_t)MID_BLKS * 8;

    const int* srcp = eidx;
    const int* dstp = eidx + N_EDGES;

    // CSR build: bucket sort (LDS-staged) + per-bucket counting sort
    hipMemsetAsync(bcnt, 0, 1024, stream);
    k_bhist<<<P1_BLKS, 256, 0, stream>>>(dstp, bcnt);
    k_bscan<<<1, 256, 0, stream>>>(bcnt, bbase, bcur);
    k_pass1<<<P1_BLKS, 256, 0, stream>>>(srcp, dstp, bcur, csr_tmp);
    k_pass2<<<NBUCK, 256, 0, stream>>>(bbase, csr_tmp, offsets, csr_se);

    k_embed<<<(N_NODES + 15) / 16, 256, 0, stream>>>(x, embW, embB, ln0w, ln0b, h, out);

    for (int l = 0; l < NL; ++l) {
        k_trans<<<(N_NODES + 7) / 8, 256, 0, stream>>>(
            h, Wl + l * NC * HC, bl + l * HC, Wr + l * NC * HC, br + l * HC, xl, xr);
        k_agg<<<AGG_BLKS, 256, 0, stream>>>(
            offsets, csr_se, (const float4*)eattr, We + l * NED * HC, att + l * HC,
            gatb + l * HC, xl, xr, g, part1);
        k_red<<<1, 256, 0, stream>>>(part1, AGG_BLKS, stats);
        k_mid<<<MID_BLKS, 256, 0, stream>>>(
            g, n1w + l * HC, n1b + l * HC,
            linW + l * HC * NC, linb + l * NC, stats, g2, part2);
        k_red<<<1, 256, 0, stream>>>(part2, MID_BLKS, stats + 2);
        k_final<<<(N_NODES * NC + 255) / 256, 256, 0, stream>>>(
            g2, n2w + l * NC, n2b + l * NC, stats + 2, h, out);
    }
}